// Round 17
// baseline (187.356 us; speedup 1.0000x reference)
//
#include <hip/hip_runtime.h>
#include <hip/hip_bf16.h>

// ModernBertAttention: B=4 S=2048 H=1024 NH=16 HD=64, rope theta=160000, f32 in/out.
// R17: QKV GEMM = R14's verified 256x128/8-wave/vmcnt(3) kernel with the K-tile
//      compute split into 4 phases (reads+stage | s_barrier | setprio MFMA) to create
//      wave role diversity (T3 gate: 8 waves + fine interleave). Math/sync identical
//      to R14. Out-proj keeps R16 gemm3<1>. attn frozen (83.5us).

#define GLOBAL_AS __attribute__((address_space(1)))
#define LDS_AS    __attribute__((address_space(3)))

using f32x4  = __attribute__((ext_vector_type(4))) float;
using f32x16 = __attribute__((ext_vector_type(16))) float;
using s16x8  = __attribute__((ext_vector_type(8))) short;

__device__ __forceinline__ void gld_lds16(const void* g, void* l) {
  __builtin_amdgcn_global_load_lds((const GLOBAL_AS void*)g, (LDS_AS void*)l, 16, 0, 0);
}

__device__ __forceinline__ unsigned short f2bf(float f) {
  unsigned int u = __float_as_uint(f);
  u = (u + 0x7fffu + ((u >> 16) & 1u)) >> 16;   // RNE
  return (unsigned short)u;
}
__device__ __forceinline__ unsigned int cvt_pk_bf16(float lo, float hi) {
  unsigned int r;
  asm("v_cvt_pk_bf16_f32 %0, %1, %2" : "=v"(r) : "v"(lo), "v"(hi));
  return r;
}
__device__ __forceinline__ void pswap(unsigned int& a, unsigned int& b) {
  asm("v_permlane32_swap_b32 %0, %1" : "+v"(a), "+v"(b));
}

// ---------- merged f32->bf16 convert + rope table (blocks >= 12288) ----------
__global__ __launch_bounds__(256) void cvt_rope_kernel(const float* __restrict__ h,
                                                       const float* __restrict__ wq,
                                                       const float* __restrict__ wo,
                                                       const int* __restrict__ pos,
                                                       unsigned short* __restrict__ hb,
                                                       unsigned short* __restrict__ wqb,
                                                       unsigned short* __restrict__ wob,
                                                       float* __restrict__ ctab,
                                                       float* __restrict__ stab) {
  int b = blockIdx.x;
  if (b >= 12288) {   // rope table: B*S*32 entries
    int idx = (b - 12288) * 256 + threadIdx.x;
    int d = idx & 31;
    int bs = idx >> 5;
    float p = (float)pos[bs];
    float inv = exp2f(-(float)d * 0.5402410118609203f);  // theta^(-d/32)
    float f = p * inv;
    ctab[idx] = cosf(f);
    stab[idx] = sinf(f);
    return;
  }
  const float* src; unsigned short* dst; int i;
  if (b < 8192)       { src = h;  dst = hb;  i = b * 256 + threadIdx.x; }
  else if (b < 11264) { src = wq; dst = wqb; i = (b - 8192) * 256 + threadIdx.x; }
  else                { src = wo; dst = wob; i = (b - 11264) * 256 + threadIdx.x; }
  float4 v = ((const float4*)src)[i];
  ushort4 o;
  o.x = f2bf(v.x); o.y = f2bf(v.y); o.z = f2bf(v.z); o.w = f2bf(v.w);
  ((ushort4*)dst)[i] = o;
}

// ------- QKV GEMM: 256x128 tile, 8 waves (4Mx2N, 64x64 wave tile), BK=64 -------
// R14 sync structure (vmcnt(3) boundary, dbuf 96KB) + 4-phase fine interleave:
// each phase = {frag reads + half-tile stage, s_barrier, setprio(1), 8 MFMA}.
// Fused epilogue: rope -> Qr/Kr (t<16); V -> Vt via LDS transpose (t>=16).
__global__ __launch_bounds__(512) void gemm8_kernel(const unsigned short* __restrict__ A,
                                                    const unsigned short* __restrict__ Bm,
                                                    int N, int K,
                                                    const float* __restrict__ ctab,
                                                    const float* __restrict__ stab,
                                                    unsigned short* __restrict__ Qr,
                                                    unsigned short* __restrict__ Kr,
                                                    unsigned short* __restrict__ Vt) {
  extern __shared__ char lds[];   // 98304 B: 2 dbuf x (A 2x16KB + B 2x8KB)
  const int tid  = threadIdx.x;
  const int lane = tid & 63, w = tid >> 6;   // 8 waves
  const int g = lane >> 4, c = lane & 15;
  const int wr = w >> 1, wc = w & 1;         // wave tile: rows wr*64, cols wc*64
  const int m0 = blockIdx.x * 256, n0 = blockIdx.y * 128;
  const char* Ab = (const char*)A;
  const char* Bb = (const char*)Bm;
  const int NKT = K >> 6;                    // 16

#define STAGE_A(kt, hh)                                                          \
  {                                                                              \
    _Pragma("unroll")                                                            \
    for (int L = 0; L < 2; ++L) {                                                \
      int o = tid * 16 + L * 8192;                                               \
      int row = o >> 7;                                                          \
      int gcol = (o & 127) ^ ((row & 7) << 4);                                   \
      gld_lds16(Ab + ((size_t)(m0 + (hh) * 128 + row) * K + (kt) * 64) * 2 + gcol,\
                lds + ((kt) & 1) * 49152 + (hh) * 16384 + o);                    \
    }                                                                            \
  }
#define STAGE_B(kt, hh)                                                          \
  {                                                                              \
    int o = tid * 16;                                                            \
    int row = o >> 7;                                                            \
    int gcol = (o & 127) ^ ((row & 7) << 4);                                     \
    gld_lds16(Bb + ((size_t)(n0 + (hh) * 64 + row) * K + (kt) * 64) * 2 + gcol,  \
              lds + ((kt) & 1) * 49152 + 32768 + (hh) * 8192 + o);               \
  }

  // prologue: kt0 complete, then kt1 first halves (group order pinned)
  STAGE_A(0, 0); STAGE_B(0, 0); STAGE_A(0, 1); STAGE_B(0, 1);
  __builtin_amdgcn_sched_barrier(0);
  STAGE_A(1, 0); STAGE_B(1, 0);
  __builtin_amdgcn_sched_barrier(0);

  f32x4 acc[4][4] = {};
  const int rA0 = (wr & 1) * 64 + c;   // A row within half (half = wr>>1)
  for (int kt = 0; kt < NKT; ++kt) {
    // boundary: wait kt's 6 loads (oldest), leave next tile's 3 in flight
    if (kt == NKT - 1) asm volatile("s_waitcnt vmcnt(0)" ::: "memory");
    else               asm volatile("s_waitcnt vmcnt(3)" ::: "memory");
    __builtin_amdgcn_sched_barrier(0);
    __builtin_amdgcn_s_barrier();
    __builtin_amdgcn_sched_barrier(0);

    const char* baseA = lds + (kt & 1) * 49152 + (wr >> 1) * 16384;
    const char* baseB = lds + (kt & 1) * 49152 + 32768 + wc * 8192;

    // ---- phase 0: reads {af rows 0,1 | bf all, ks=0}; stage A-half1(kt+1); 8 MFMA ----
    s16x8 b0[4], aP[2];
#pragma unroll
    for (int j = 0; j < 4; ++j) {
      int row = 16 * j + c;
      b0[j] = *(const s16x8*)(baseB + ((row * 128 + g * 16) ^ ((row & 7) << 4)));
    }
#pragma unroll
    for (int i = 0; i < 2; ++i) {
      int row = rA0 + 16 * i;
      aP[i] = *(const s16x8*)(baseA + ((row * 128 + g * 16) ^ ((row & 7) << 4)));
    }
    if (kt + 1 < NKT) STAGE_A(kt + 1, 1);
    __builtin_amdgcn_sched_barrier(0);
    __builtin_amdgcn_s_barrier();
    __builtin_amdgcn_s_setprio(1);
#pragma unroll
    for (int i = 0; i < 2; ++i)
#pragma unroll
      for (int j = 0; j < 4; ++j)
        acc[i][j] = __builtin_amdgcn_mfma_f32_16x16x32_bf16(aP[i], b0[j], acc[i][j], 0, 0, 0);
    __builtin_amdgcn_s_setprio(0);

    // ---- phase 1: reads {af rows 2,3, ks=0}; stage B-half1(kt+1); 8 MFMA ----
    s16x8 aQ[2];
#pragma unroll
    for (int i = 0; i < 2; ++i) {
      int row = rA0 + 16 * (i + 2);
      aQ[i] = *(const s16x8*)(baseA + ((row * 128 + g * 16) ^ ((row & 7) << 4)));
    }
    if (kt + 1 < NKT) STAGE_B(kt + 1, 1);
    __builtin_amdgcn_sched_barrier(0);
    __builtin_amdgcn_s_barrier();
    __builtin_amdgcn_s_setprio(1);
#pragma unroll
    for (int i = 0; i < 2; ++i)
#pragma unroll
      for (int j = 0; j < 4; ++j)
        acc[i + 2][j] = __builtin_amdgcn_mfma_f32_16x16x32_bf16(aQ[i], b0[j], acc[i + 2][j], 0, 0, 0);
    __builtin_amdgcn_s_setprio(0);

    // ---- phase 2: reads {af rows 0,1 | bf all, ks=1}; 8 MFMA ----
    s16x8 b1[4], aR[2];
#pragma unroll
    for (int j = 0; j < 4; ++j) {
      int row = 16 * j + c;
      b1[j] = *(const s16x8*)(baseB + ((row * 128 + 64 + g * 16) ^ ((row & 7) << 4)));
    }
#pragma unroll
    for (int i = 0; i < 2; ++i) {
      int row = rA0 + 16 * i;
      aR[i] = *(const s16x8*)(baseA + ((row * 128 + 64 + g * 16) ^ ((row & 7) << 4)));
    }
    __builtin_amdgcn_sched_barrier(0);
    __builtin_amdgcn_s_barrier();
    __builtin_amdgcn_s_setprio(1);
#pragma unroll
    for (int i = 0; i < 2; ++i)
#pragma unroll
      for (int j = 0; j < 4; ++j)
        acc[i][j] = __builtin_amdgcn_mfma_f32_16x16x32_bf16(aR[i], b1[j], acc[i][j], 0, 0, 0);
    __builtin_amdgcn_s_setprio(0);

    // ---- phase 3: reads {af rows 2,3, ks=1}; 8 MFMA ----
    s16x8 aS[2];
#pragma unroll
    for (int i = 0; i < 2; ++i) {
      int row = rA0 + 16 * (i + 2);
      aS[i] = *(const s16x8*)(baseA + ((row * 128 + 64 + g * 16) ^ ((row & 7) << 4)));
    }
    __builtin_amdgcn_sched_barrier(0);
    __builtin_amdgcn_s_barrier();
    __builtin_amdgcn_s_setprio(1);
#pragma unroll
    for (int i = 0; i < 2; ++i)
#pragma unroll
      for (int j = 0; j < 4; ++j)
        acc[i + 2][j] = __builtin_amdgcn_mfma_f32_16x16x32_bf16(aS[i], b1[j], acc[i + 2][j], 0, 0, 0);
    __builtin_amdgcn_s_setprio(0);

    // ---- end of K-tile: all waves done reading dbuf[kt&1]; restage it ----
    __builtin_amdgcn_sched_barrier(0);
    __builtin_amdgcn_s_barrier();
    __builtin_amdgcn_sched_barrier(0);
    if (kt + 2 < NKT) {
      STAGE_A(kt + 2, 0);
      STAGE_B(kt + 2, 0);
      __builtin_amdgcn_sched_barrier(0);
    }
  }
#undef STAGE_A
#undef STAGE_B

  const int t = blockIdx.y;   // 0..7 Q, 8..15 K, 16..23 V (128 cols each)
  if (t < 16) {
    unsigned short* dstb = (t < 8) ? Qr : Kr;
    const float qs = (t < 8) ? 0.18033688011112042f : 1.0f;  // SCALE*log2(e) on Q
    const int h = 2 * (t & 7) + wc;
#pragma unroll
    for (int i = 0; i < 4; ++i)
#pragma unroll
      for (int r = 0; r < 4; ++r) {
        int m = m0 + wr * 64 + 16 * i + 4 * g + r;
        int b = m >> 11, s = m & 2047;
        unsigned short* drow = dstb + ((size_t)(b * 16 + h) * 2048 + s) * 64;
#pragma unroll
        for (int j = 0; j < 2; ++j) {
          int d = 16 * j + c;
          float co = ctab[(size_t)m * 32 + d];
          float si = stab[(size_t)m * 32 + d];
          float x1 = acc[i][j][r], x2 = acc[i][j + 2][r];
          drow[d]      = f2bf((x1 * co - x2 * si) * qs);
          drow[d + 32] = f2bf((x2 * co + x1 * si) * qs);
        }
      }
  } else {
    // V epilogue: 2 heads/block (head = wc); transpose 256s x 64d via LDS.
    // tile uses lds[0..36864) = dbuf0; final K-tile (kt=15, odd) read dbuf1 -> no overlap.
    unsigned short (*tile)[72] = (unsigned short (*)[72])lds;
    const int bb = m0 >> 11, sb = m0 & 2047;
#pragma unroll
    for (int hp = 0; hp < 2; ++hp) {
      __syncthreads();
      if (wc == hp) {
#pragma unroll
        for (int i = 0; i < 4; ++i)
#pragma unroll
          for (int j = 0; j < 4; ++j)
#pragma unroll
            for (int r = 0; r < 4; ++r)
              tile[wr * 64 + 16 * i + 4 * g + r][16 * j + c] = f2bf(acc[i][j][r]);
      }
      __syncthreads();
      int hh = 2 * (t - 16) + hp;
      int d = tid >> 3, p = tid & 7;           // d 0..63, p = s-chunk (32 s each)
      alignas(16) unsigned short vv[32];
#pragma unroll
      for (int i2 = 0; i2 < 32; ++i2) vv[i2] = tile[p * 32 + i2][d];
      unsigned short* dst = Vt + ((size_t)(bb * 16 + hh) * 64 + d) * 2048 + sb + p * 32;
#pragma unroll
      for (int q4 = 0; q4 < 4; ++q4)
        *(uint4*)(dst + 8 * q4) = ((const uint4*)vv)[q4];
    }
  }
}

// ---- out-proj GEMM (R16): 256x64 block, 4 waves (64x64 wave tile), BK=64, f32 C ----
__global__ __launch_bounds__(256, 2) void gemm3_kernel(const unsigned short* __restrict__ A,
                                                       const unsigned short* __restrict__ Bm,
                                                       float* __restrict__ C, int N, int K) {
  extern __shared__ char lds[];   // 81920 B: 2 dbuf x (A 32KB + B 8KB)
  const int tid  = threadIdx.x;
  const int lane = tid & 63, w = tid >> 6;
  const int g = lane >> 4, c = lane & 15;
  const int m0 = blockIdx.x * 256, n0 = blockIdx.y * 64;
  const char* Ab = (const char*)A;
  const char* Bb = (const char*)Bm;
  const int NKT = K >> 6;

#define STAGE_A(kt, hh)                                                           \
  {                                                                               \
    _Pragma("unroll")                                                             \
    for (int L = 0; L < 4; ++L) {                                                 \
      int o = tid * 16 + L * 4096;                                                \
      int row = o >> 7;                                                           \
      int gcol = (o & 127) ^ ((row & 7) << 4);                                    \
      gld_lds16(Ab + ((size_t)(m0 + (hh) * 128 + row) * K + (kt) * 64) * 2 + gcol,\
                lds + ((kt) & 1) * 40960 + (hh) * 16384 + o);                     \
    }                                                                             \
  }
#define STAGE_B(kt)                                                               \
  {                                                                               \
    _Pragma("unroll")                                                             \
    for (int L = 0; L < 2; ++L) {                                                 \
      int o = tid * 16 + L * 4096;                                                \
      int row = o >> 7;                                                           \
      int gcol = (o & 127) ^ ((row & 7) << 4);                                    \
      gld_lds16(Bb + ((size_t)(n0 + row) * K + (kt) * 64) * 2 + gcol,             \
                lds + ((kt) & 1) * 40960 + 32768 + o);                            \
    }                                                                             \
  }

  STAGE_A(0, 0); STAGE_A(0, 1); STAGE_B(0);
  __builtin_amdgcn_sched_barrier(0);
  STAGE_A(1, 0);
  __builtin_amdgcn_sched_barrier(0);

  f32x4 acc[4][4] = {};
  for (int kt = 0; kt < NKT; ++kt) {
    if (kt == 0 || kt == NKT - 1) asm volatile("s_waitcnt vmcnt(0)" ::: "memory");
    else                          asm volatile("s_waitcnt vmcnt(4)" ::: "memory");
    __builtin_amdgcn_sched_barrier(0);
    __builtin_amdgcn_s_barrier();
    __builtin_amdgcn_sched_barrier(0);

    const char* baseA = lds + (kt & 1) * 40960;
    const char* baseB = baseA + 32768;

    s16x8 af[4][2], bf[4][2];
#pragma unroll
    for (int i = 0; i < 4; ++i) {
      int row = w * 64 + 16 * i + c;
#pragma unroll
      for (int ks = 0; ks < 2; ++ks)
        af[i][ks] = *(const s16x8*)(baseA + ((row * 128 + ks * 64 + g * 16) ^ ((row & 7) << 4)));
    }
#pragma unroll
    for (int j = 0; j < 4; ++j) {
      int row = 16 * j + c;
#pragma unroll
      for (int ks = 0; ks < 2; ++ks)
        bf[j][ks] = *(const s16x8*)(baseB + ((row * 128 + ks * 64 + g * 16) ^ ((row & 7) << 4)));
    }

    if (kt + 1 < NKT) {
      STAGE_A(kt + 1, 1);
      STAGE_B(kt + 1);
    }
    __builtin_amdgcn_sched_barrier(0);

    __builtin_amdgcn_s_setprio(1);
#pragma unroll
    for (int ks = 0; ks < 2; ++ks)
#pragma unroll
      for (int i = 0; i < 4; ++i)
#pragma unroll
        for (int j = 0; j < 4; ++j)
          acc[i][j] = __builtin_amdgcn_mfma_f32_16x16x32_bf16(af[i][ks], bf[j][ks], acc[i][j], 0, 0, 0);
    __builtin_amdgcn_s_setprio(0);

    __builtin_amdgcn_sched_barrier(0);
    __builtin_amdgcn_s_barrier();
    __builtin_amdgcn_sched_barrier(0);
    if (kt + 2 < NKT) {
      STAGE_A(kt + 2, 0);
      __builtin_amdgcn_sched_barrier(0);
    }
  }
#undef STAGE_A
#undef STAGE_B

#pragma unroll
  for (int i = 0; i < 4; ++i)
#pragma unroll
    for (int j = 0; j < 4; ++j)
#pragma unroll
      for (int r = 0; r < 4; ++r) {
        int m = m0 + w * 64 + 16 * i + 4 * g + r;
        int n = n0 + 16 * j + c;
        C[(size_t)m * N + n] = acc[i][j][r];
      }
}

// ---------------- flash attention: 256 q/block, 8 waves x 32 q, 32x32x16 MFMA ----------------
// (frozen at R11/R13) Triple-buffered K/V; counted vmcnt(2); one raw barrier/iter; in-reg P.
__global__ __launch_bounds__(512) void attn_kernel(const unsigned short* __restrict__ Q,
                                                   const unsigned short* __restrict__ Kr,
                                                   const unsigned short* __restrict__ Vt,
                                                   unsigned short* __restrict__ Ctx) {
  __shared__ char sK[3][8192];   // 64 kv rows x 128B, swizzle (row&7)<<4
  __shared__ char sV[3][8192];   // 64 d rows x 128B (V^T tile)
  const int tid  = threadIdx.x;
  const int lane = tid & 63, w = tid >> 6;       // w in 0..7
  const int hi = lane >> 5, ql = lane & 31;
  const int swz = (ql & 7) << 4;
  int lin = blockIdx.x + 8 * blockIdx.y;         // grid (8, 64) = 512 blocks
  int eff = (lin & 7) * 64 + (lin >> 3);
  const int bh = eff >> 3;                       // 0..63
  const int q0 = (eff & 7) * 256;
  const char* kh = (const char*)(Kr + (size_t)bh * 2048 * 64);
  const char* vh = (const char*)(Vt + (size_t)bh * 64 * 2048);

  s16x8 qf[4];
  {
    const char* qrow = (const char*)Q + ((size_t)bh * 2048 + q0 + 32 * w + ql) * 128;
#pragma unroll
    for (int t = 0; t < 4; ++t) qf[t] = *(const s16x8*)(qrow + t * 32 + hi * 16);
  }
  __builtin_amdgcn_sched_barrier(0);   // qf loads issued before any STAGE

#define STAGE(t, b)                                                              \
  {                                                                              \
    int o = tid * 16;                                                            \
    int l = o ^ (((o >> 7) & 7) << 4);                                           \
    gld_lds16(kh + (size_t)(t) * 8192 + l, sK[b] + o);                           \
    gld_lds16(vh + (size_t)(o >> 7) * 4096 + (t) * 128 + (l & 127), sV[b] + o);  \
  }

  STAGE(0, 0);
  __builtin_amdgcn_sched_barrier(0);
  STAGE(1, 1);
  __builtin_amdgcn_sched_barrier(0);

  float l_run = 0.f;
  f32x16 oa0 = {}, oa1 = {};   // D[d][q]: d 0-31, d 32-63
  int cur = 0;

  for (int it = 0; it < 32; ++it) {
    if (it == 0 || it == 31) asm volatile("s_waitcnt vmcnt(0)" ::: "memory");
    else                     asm volatile("s_waitcnt vmcnt(2)" ::: "memory");
    __builtin_amdgcn_sched_barrier(0);
    __builtin_amdgcn_s_barrier();
    __builtin_amdgcn_sched_barrier(0);

    if (it + 2 < 32) {
      int sb = cur + 2; if (sb >= 3) sb -= 3;
      STAGE(it + 2, sb);
    }
    __builtin_amdgcn_sched_barrier(0);

    f32x16 sc0 = {}, sc1 = {};
    __builtin_amdgcn_s_setprio(1);
#pragma unroll
    for (int t = 0; t < 4; ++t) {
      int cx = (t * 32 + hi * 16) ^ swz;
      s16x8 k0 = *(const s16x8*)(sK[cur] + ql * 128 + cx);
      s16x8 k1 = *(const s16x8*)(sK[cur] + (32 + ql) * 128 + cx);
      sc0 = __builtin_amdgcn_mfma_f32_32x32x16_bf16(k0, qf[t], sc0, 0, 0, 0);
      sc1 = __builtin_amdgcn_mfma_f32_32x32x16_bf16(k1, qf[t], sc1, 0, 0, 0);
    }
    __builtin_amdgcn_s_setprio(0);

    float rs = 0.f;
#pragma unroll
    for (int r = 0; r < 16; ++r) { sc0[r] = __builtin_amdgcn_exp2f(sc0[r]); rs += sc0[r]; }
#pragma unroll
    for (int r = 0; r < 16; ++r) { sc1[r] = __builtin_amdgcn_exp2f(sc1[r]); rs += sc1[r]; }
    l_run += rs;

    unsigned int bp[16];
#pragma unroll
    for (int blk = 0; blk < 2; ++blk) {
      const f32x16& s = blk ? sc1 : sc0;
      unsigned int a0 = cvt_pk_bf16(s[0],  s[1]);
      unsigned int a1 = cvt_pk_bf16(s[2],  s[3]);
      unsigned int a2 = cvt_pk_bf16(s[4],  s[5]);
      unsigned int a3 = cvt_pk_bf16(s[6],  s[7]);
      pswap(a0, a2); pswap(a1, a3);
      bp[blk * 8 + 0] = a0; bp[blk * 8 + 1] = a1;
      bp[blk * 8 + 2] = a2; bp[blk * 8 + 3] = a3;
      unsigned int b0 = cvt_pk_bf16(s[8],  s[9]);
      unsigned int b1 = cvt_pk_bf16(s[10], s[11]);
      unsigned int b2 = cvt_pk_bf16(s[12], s[13]);
      unsigned int b3 = cvt_pk_bf16(s[14], s[15]);
      pswap(b0, b2); pswap(b1, b3);
      bp[blk * 8 + 4] = b0; bp[blk * 8 + 5] = b1;
      bp[blk * 8 + 6] = b2; bp[blk * 8 + 7] = b3;
    }

    __builtin_amdgcn_s_setprio(1);
#pragma unroll
    for (int ss = 0; ss < 4; ++ss) {
      uint4 u = {bp[ss * 4], bp[ss * 4 + 1], bp[ss * 4 + 2], bp[ss * 4 + 3]};
      s16x8 pb = __builtin_bit_cast(s16x8, u);
      int cx = (ss * 32 + hi * 16) ^ swz;
      s16x8 v0 = *(const s16x8*)(sV[cur] + ql * 128 + cx);
      s16x8 v1 = *(const s16x8*)(sV[cur] + (32 + ql) * 128 + cx);
      oa0 = __builtin_amdgcn_mfma_f32_32x32x16_bf16(v0, pb, oa0, 0, 0, 0);
      oa1 = __builtin_amdgcn_mfma_f32_32x32x16_bf16(v1, pb, oa1, 0, 0, 0);
    }
    __builtin_amdgcn_s_setprio(0);

    ++cur; if (cur == 3) cur = 0;
  }
#undef STAGE

  l_run += __shfl_xor(l_run, 32);
  float inv = 1.f / l_run;
  const int b = bh >> 4, h = bh & 15;
  const int q = q0 + 32 * w + ql;
  unsigned short* crow = Ctx + ((size_t)(b * 2048 + q)) * 1024 + h * 64;
#pragma unroll
  for (int dblk = 0; dblk < 2; ++dblk) {
    const f32x16& oa = dblk ? oa1 : oa0;
#pragma unroll
    for (int grp = 0; grp < 4; ++grp) {
      ushort4 st;
      st.x = f2bf(oa[4 * grp + 0] * inv);
      st.y = f2bf(oa[4 * grp + 1] * inv);
      st.z = f2bf(oa[4 * grp + 2] * inv);
      st.w = f2bf(oa[4 * grp + 3] * inv);
      *(ushort4*)(crow + dblk * 32 + 8 * grp + 4 * hi) = st;
    }
  }
}

extern "C" void kernel_launch(void* const* d_in, const int* in_sizes, int n_in,
                              void* d_out, int out_size, void* d_ws, size_t ws_size,
                              hipStream_t stream) {
  const float* hidden = (const float*)d_in[0];   // (4,2048,1024) f32
  const int*   pos    = (const int*)d_in[1];     // (4,2048) i32
  const float* wqkv   = (const float*)d_in[2];   // (3072,1024) f32
  const float* wo     = (const float*)d_in[3];   // (1024,1024) f32

  char* ws = (char*)d_ws;
  unsigned short* hbf  = (unsigned short*)(ws);                 // 16,777,216 B
  unsigned short* wqbf = (unsigned short*)(ws + 16777216);      //  6,291,456
  unsigned short* wobf = (unsigned short*)(ws + 23068672);      //  2,097,152
  unsigned short* Qr   = (unsigned short*)(ws + 41943040);      // 16,777,216
  unsigned short* Kr   = (unsigned short*)(ws + 58720256);      // 16,777,216
  unsigned short* Vt   = (unsigned short*)(ws + 75497472);      // 16,777,216
  unsigned short* ctx  = (unsigned short*)(ws + 92274688);      // 16,777,216
  float*          ctab = (float*)(ws + 109051904);              //  1,048,576
  float*          stab = (float*)(ws + 110100480);              //  1,048,576
  // total: 111,149,056 B

  cvt_rope_kernel<<<13312, 256, 0, stream>>>(hidden, wqkv, wo, pos,
                                             hbf, wqbf, wobf, ctab, stab);

  dim3 gq(32, 24);
  gemm8_kernel<<<gq, 512, 98304, stream>>>(hbf, wqbf, 3072, 1024,
                                           ctab, stab, Qr, Kr, Vt);

  dim3 ga(8, 64);
  attn_kernel<<<ga, 512, 0, stream>>>(Qr, Kr, Vt, ctx);

  dim3 go(32, 16);
  gemm3_kernel<<<go, 256, 81920, stream>>>(ctx, wobf, (float*)d_out, 1024, 1024);
}

// Round 18
// 178.780 us; speedup vs baseline: 1.0480x; 1.0480x over previous
//
#include <hip/hip_runtime.h>
#include <hip/hip_bf16.h>

// ModernBertAttention: B=4 S=2048 H=1024 NH=16 HD=64, rope theta=160000, f32 in/out.
// R18: exact revert to R16 (best: 179.2us). R17's 4-phase split regressed (-8us),
//      confirming the 2-barrier + counted-vmcnt + 2-blocks/CU GEMM is the local
//      optimum for these shapes. attn frozen (83.5us). cvt_rope at HBM roofline.

#define GLOBAL_AS __attribute__((address_space(1)))
#define LDS_AS    __attribute__((address_space(3)))

using f32x4  = __attribute__((ext_vector_type(4))) float;
using f32x16 = __attribute__((ext_vector_type(16))) float;
using s16x8  = __attribute__((ext_vector_type(8))) short;

__device__ __forceinline__ void gld_lds16(const void* g, void* l) {
  __builtin_amdgcn_global_load_lds((const GLOBAL_AS void*)g, (LDS_AS void*)l, 16, 0, 0);
}

__device__ __forceinline__ unsigned short f2bf(float f) {
  unsigned int u = __float_as_uint(f);
  u = (u + 0x7fffu + ((u >> 16) & 1u)) >> 16;   // RNE
  return (unsigned short)u;
}
__device__ __forceinline__ unsigned int cvt_pk_bf16(float lo, float hi) {
  unsigned int r;
  asm("v_cvt_pk_bf16_f32 %0, %1, %2" : "=v"(r) : "v"(lo), "v"(hi));
  return r;
}
__device__ __forceinline__ void pswap(unsigned int& a, unsigned int& b) {
  asm("v_permlane32_swap_b32 %0, %1" : "+v"(a), "+v"(b));
}

// ---------- merged f32->bf16 convert + rope table (blocks >= 12288) ----------
__global__ __launch_bounds__(256) void cvt_rope_kernel(const float* __restrict__ h,
                                                       const float* __restrict__ wq,
                                                       const float* __restrict__ wo,
                                                       const int* __restrict__ pos,
                                                       unsigned short* __restrict__ hb,
                                                       unsigned short* __restrict__ wqb,
                                                       unsigned short* __restrict__ wob,
                                                       float* __restrict__ ctab,
                                                       float* __restrict__ stab) {
  int b = blockIdx.x;
  if (b >= 12288) {   // rope table: B*S*32 entries
    int idx = (b - 12288) * 256 + threadIdx.x;
    int d = idx & 31;
    int bs = idx >> 5;
    float p = (float)pos[bs];
    float inv = exp2f(-(float)d * 0.5402410118609203f);  // theta^(-d/32)
    float f = p * inv;
    ctab[idx] = cosf(f);
    stab[idx] = sinf(f);
    return;
  }
  const float* src; unsigned short* dst; int i;
  if (b < 8192)       { src = h;  dst = hb;  i = b * 256 + threadIdx.x; }
  else if (b < 11264) { src = wq; dst = wqb; i = (b - 8192) * 256 + threadIdx.x; }
  else                { src = wo; dst = wob; i = (b - 11264) * 256 + threadIdx.x; }
  float4 v = ((const float4*)src)[i];
  ushort4 o;
  o.x = f2bf(v.x); o.y = f2bf(v.y); o.z = f2bf(v.z); o.w = f2bf(v.w);
  ((ushort4*)dst)[i] = o;
}

// ---- GEMM C[m,n]=sum_k A[m,k]B[n,k]: 256x64 block, 4 waves (64x64 wave tile), BK=64 ----
// 80KB dbuf LDS (2 blocks/CU). 16 ds_read_b128 : 32 MFMA per wave per K-tile.
// Counted vmcnt(4): next tile's A-half0 (4 loads) stays in flight across barriers.
// MODE 1: f32 C. MODE 2: QKV epilogue, 1 head/block (rope -> Qr/Kr; V -> Vt transpose).
template<int MODE>
__global__ __launch_bounds__(256, 2) void gemm3_kernel(const unsigned short* __restrict__ A,
                                                       const unsigned short* __restrict__ Bm,
                                                       void* __restrict__ C, int N, int K,
                                                       const float* __restrict__ ctab,
                                                       const float* __restrict__ stab,
                                                       unsigned short* __restrict__ Qr,
                                                       unsigned short* __restrict__ Kr,
                                                       unsigned short* __restrict__ Vt) {
  extern __shared__ char lds[];   // 81920 B: 2 dbuf x (A 32KB + B 8KB)
  const int tid  = threadIdx.x;
  const int lane = tid & 63, w = tid >> 6;   // 4 waves, wave rows w*64..w*64+63
  const int g = lane >> 4, c = lane & 15;
  const int m0 = blockIdx.x * 256, n0 = blockIdx.y * 64;
  const char* Ab = (const char*)A;
  const char* Bb = (const char*)Bm;
  const int NKT = K >> 6;                    // 16

  // A-half hh (128 rows x 128B = 16KB, 4 loads/thread) of K-tile kt
#define STAGE_A(kt, hh)                                                           \
  {                                                                               \
    _Pragma("unroll")                                                             \
    for (int L = 0; L < 4; ++L) {                                                 \
      int o = tid * 16 + L * 4096;                                                \
      int row = o >> 7;                                                           \
      int gcol = (o & 127) ^ ((row & 7) << 4);                                    \
      gld_lds16(Ab + ((size_t)(m0 + (hh) * 128 + row) * K + (kt) * 64) * 2 + gcol,\
                lds + ((kt) & 1) * 40960 + (hh) * 16384 + o);                     \
    }                                                                             \
  }
  // B tile (64 rows x 128B = 8KB, 2 loads/thread)
#define STAGE_B(kt)                                                               \
  {                                                                               \
    _Pragma("unroll")                                                             \
    for (int L = 0; L < 2; ++L) {                                                 \
      int o = tid * 16 + L * 4096;                                                \
      int row = o >> 7;                                                           \
      int gcol = (o & 127) ^ ((row & 7) << 4);                                    \
      gld_lds16(Bb + ((size_t)(n0 + row) * K + (kt) * 64) * 2 + gcol,             \
                lds + ((kt) & 1) * 40960 + 32768 + o);                            \
    }                                                                             \
  }

  // prologue: kt0 complete (10 loads/thread), then kt1 A-half0 (4)
  STAGE_A(0, 0); STAGE_A(0, 1); STAGE_B(0);
  __builtin_amdgcn_sched_barrier(0);
  STAGE_A(1, 0);
  __builtin_amdgcn_sched_barrier(0);

  f32x4 acc[4][4] = {};
  for (int kt = 0; kt < NKT; ++kt) {
    // boundary: drain kt's 10 loads (oldest), leave kt+1's A-half0 (4) in flight
    if (kt == 0 || kt == NKT - 1) asm volatile("s_waitcnt vmcnt(0)" ::: "memory");
    else                          asm volatile("s_waitcnt vmcnt(4)" ::: "memory");
    __builtin_amdgcn_sched_barrier(0);
    __builtin_amdgcn_s_barrier();
    __builtin_amdgcn_sched_barrier(0);

    const char* baseA = lds + (kt & 1) * 40960;
    const char* baseB = baseA + 32768;

    s16x8 af[4][2], bf[4][2];
#pragma unroll
    for (int i = 0; i < 4; ++i) {
      int row = w * 64 + 16 * i + c;
#pragma unroll
      for (int ks = 0; ks < 2; ++ks)
        af[i][ks] = *(const s16x8*)(baseA + ((row * 128 + ks * 64 + g * 16) ^ ((row & 7) << 4)));
    }
#pragma unroll
    for (int j = 0; j < 4; ++j) {
      int row = 16 * j + c;
#pragma unroll
      for (int ks = 0; ks < 2; ++ks)
        bf[j][ks] = *(const s16x8*)(baseB + ((row * 128 + ks * 64 + g * 16) ^ ((row & 7) << 4)));
    }

    if (kt + 1 < NKT) {   // stage kt+1's A-half1 + B (other dbuf; no race)
      STAGE_A(kt + 1, 1);
      STAGE_B(kt + 1);
    }
    __builtin_amdgcn_sched_barrier(0);

    __builtin_amdgcn_s_setprio(1);
#pragma unroll
    for (int ks = 0; ks < 2; ++ks)
#pragma unroll
      for (int i = 0; i < 4; ++i)
#pragma unroll
        for (int j = 0; j < 4; ++j)
          acc[i][j] = __builtin_amdgcn_mfma_f32_16x16x32_bf16(af[i][ks], bf[j][ks], acc[i][j], 0, 0, 0);
    __builtin_amdgcn_s_setprio(0);

    __builtin_amdgcn_sched_barrier(0);
    __builtin_amdgcn_s_barrier();   // all waves done reading dbuf[kt&1]
    __builtin_amdgcn_sched_barrier(0);
    if (kt + 2 < NKT) {             // restage freed buffer: kt+2's A-half0
      STAGE_A(kt + 2, 0);
      __builtin_amdgcn_sched_barrier(0);
    }
  }
#undef STAGE_A
#undef STAGE_B

  if (MODE == 1) {
#pragma unroll
    for (int i = 0; i < 4; ++i)
#pragma unroll
      for (int j = 0; j < 4; ++j)
#pragma unroll
        for (int r = 0; r < 4; ++r) {
          int m = m0 + w * 64 + 16 * i + 4 * g + r;
          int n = n0 + 16 * j + c;
          ((float*)C)[(size_t)m * N + n] = acc[i][j][r];
        }
  } else {
    const int t = blockIdx.y;   // 0..15 Q head t, 16..31 K head t-16, 32..47 V head t-32
    if (t < 32) {
      unsigned short* dstb = (t < 16) ? Qr : Kr;
      const float qs = (t < 16) ? 0.18033688011112042f : 1.0f;  // SCALE*log2(e) on Q
      const int h = t & 15;
#pragma unroll
      for (int i = 0; i < 4; ++i)
#pragma unroll
        for (int r = 0; r < 4; ++r) {
          int m = m0 + w * 64 + 16 * i + 4 * g + r;
          int b = m >> 11, s = m & 2047;
          unsigned short* drow = dstb + ((size_t)(b * 16 + h) * 2048 + s) * 64;
#pragma unroll
          for (int j = 0; j < 2; ++j) {
            int d = 16 * j + c;
            float co = ctab[(size_t)m * 32 + d];
            float si = stab[(size_t)m * 32 + d];
            float x1 = acc[i][j][r], x2 = acc[i][j + 2][r];
            drow[d]      = f2bf((x1 * co - x2 * si) * qs);
            drow[d + 32] = f2bf((x2 * co + x1 * si) * qs);
          }
        }
    } else {
      // V epilogue: head h = t-32; transpose 256s x 64d via LDS, write Vt directly.
      unsigned short (*tile)[72] = (unsigned short (*)[72])lds;
      const int bb = m0 >> 11, sb = m0 & 2047;
      const int h = t - 32;
#pragma unroll
      for (int i = 0; i < 4; ++i)
#pragma unroll
        for (int j = 0; j < 4; ++j)
#pragma unroll
          for (int r = 0; r < 4; ++r)
            tile[w * 64 + 16 * i + 4 * g + r][16 * j + c] = f2bf(acc[i][j][r]);
      __syncthreads();
      int d = tid >> 2, p = tid & 3;             // d 0..63, p = s-chunk (64 s each)
      unsigned short* dst = Vt + ((size_t)(bb * 16 + h) * 64 + d) * 2048 + sb + p * 64;
#pragma unroll
      for (int q8 = 0; q8 < 8; ++q8) {
        alignas(16) unsigned short tmp[8];
#pragma unroll
        for (int i2 = 0; i2 < 8; ++i2) tmp[i2] = tile[p * 64 + q8 * 8 + i2][d];
        *(uint4*)(dst + q8 * 8) = *(const uint4*)tmp;
      }
    }
  }
}

// ---------------- flash attention: 256 q/block, 8 waves x 32 q, 32x32x16 MFMA ----------------
// (frozen at R11/R13) Triple-buffered K/V; counted vmcnt(2); one raw barrier/iter; in-reg P.
__global__ __launch_bounds__(512) void attn_kernel(const unsigned short* __restrict__ Q,
                                                   const unsigned short* __restrict__ Kr,
                                                   const unsigned short* __restrict__ Vt,
                                                   unsigned short* __restrict__ Ctx) {
  __shared__ char sK[3][8192];   // 64 kv rows x 128B, swizzle (row&7)<<4
  __shared__ char sV[3][8192];   // 64 d rows x 128B (V^T tile)
  const int tid  = threadIdx.x;
  const int lane = tid & 63, w = tid >> 6;       // w in 0..7
  const int hi = lane >> 5, ql = lane & 31;
  const int swz = (ql & 7) << 4;
  int lin = blockIdx.x + 8 * blockIdx.y;         // grid (8, 64) = 512 blocks
  int eff = (lin & 7) * 64 + (lin >> 3);
  const int bh = eff >> 3;                       // 0..63
  const int q0 = (eff & 7) * 256;
  const char* kh = (const char*)(Kr + (size_t)bh * 2048 * 64);
  const char* vh = (const char*)(Vt + (size_t)bh * 64 * 2048);

  s16x8 qf[4];
  {
    const char* qrow = (const char*)Q + ((size_t)bh * 2048 + q0 + 32 * w + ql) * 128;
#pragma unroll
    for (int t = 0; t < 4; ++t) qf[t] = *(const s16x8*)(qrow + t * 32 + hi * 16);
  }
  __builtin_amdgcn_sched_barrier(0);   // qf loads issued before any STAGE

#define STAGE(t, b)                                                              \
  {                                                                              \
    int o = tid * 16;                                                            \
    int l = o ^ (((o >> 7) & 7) << 4);                                           \
    gld_lds16(kh + (size_t)(t) * 8192 + l, sK[b] + o);                           \
    gld_lds16(vh + (size_t)(o >> 7) * 4096 + (t) * 128 + (l & 127), sV[b] + o);  \
  }

  STAGE(0, 0);
  __builtin_amdgcn_sched_barrier(0);
  STAGE(1, 1);
  __builtin_amdgcn_sched_barrier(0);

  float l_run = 0.f;
  f32x16 oa0 = {}, oa1 = {};   // D[d][q]: d 0-31, d 32-63
  int cur = 0;

  for (int it = 0; it < 32; ++it) {
    if (it == 0 || it == 31) asm volatile("s_waitcnt vmcnt(0)" ::: "memory");
    else                     asm volatile("s_waitcnt vmcnt(2)" ::: "memory");
    __builtin_amdgcn_sched_barrier(0);
    __builtin_amdgcn_s_barrier();
    __builtin_amdgcn_sched_barrier(0);

    if (it + 2 < 32) {
      int sb = cur + 2; if (sb >= 3) sb -= 3;
      STAGE(it + 2, sb);
    }
    __builtin_amdgcn_sched_barrier(0);

    f32x16 sc0 = {}, sc1 = {};
    __builtin_amdgcn_s_setprio(1);
#pragma unroll
    for (int t = 0; t < 4; ++t) {
      int cx = (t * 32 + hi * 16) ^ swz;
      s16x8 k0 = *(const s16x8*)(sK[cur] + ql * 128 + cx);
      s16x8 k1 = *(const s16x8*)(sK[cur] + (32 + ql) * 128 + cx);
      sc0 = __builtin_amdgcn_mfma_f32_32x32x16_bf16(k0, qf[t], sc0, 0, 0, 0);
      sc1 = __builtin_amdgcn_mfma_f32_32x32x16_bf16(k1, qf[t], sc1, 0, 0, 0);
    }
    __builtin_amdgcn_s_setprio(0);

    float rs = 0.f;
#pragma unroll
    for (int r = 0; r < 16; ++r) { sc0[r] = __builtin_amdgcn_exp2f(sc0[r]); rs += sc0[r]; }
#pragma unroll
    for (int r = 0; r < 16; ++r) { sc1[r] = __builtin_amdgcn_exp2f(sc1[r]); rs += sc1[r]; }
    l_run += rs;

    unsigned int bp[16];
#pragma unroll
    for (int blk = 0; blk < 2; ++blk) {
      const f32x16& s = blk ? sc1 : sc0;
      unsigned int a0 = cvt_pk_bf16(s[0],  s[1]);
      unsigned int a1 = cvt_pk_bf16(s[2],  s[3]);
      unsigned int a2 = cvt_pk_bf16(s[4],  s[5]);
      unsigned int a3 = cvt_pk_bf16(s[6],  s[7]);
      pswap(a0, a2); pswap(a1, a3);
      bp[blk * 8 + 0] = a0; bp[blk * 8 + 1] = a1;
      bp[blk * 8 + 2] = a2; bp[blk * 8 + 3] = a3;
      unsigned int b0 = cvt_pk_bf16(s[8],  s[9]);
      unsigned int b1 = cvt_pk_bf16(s[10], s[11]);
      unsigned int b2 = cvt_pk_bf16(s[12], s[13]);
      unsigned int b3 = cvt_pk_bf16(s[14], s[15]);
      pswap(b0, b2); pswap(b1, b3);
      bp[blk * 8 + 4] = b0; bp[blk * 8 + 5] = b1;
      bp[blk * 8 + 6] = b2; bp[blk * 8 + 7] = b3;
    }

    __builtin_amdgcn_s_setprio(1);
#pragma unroll
    for (int ss = 0; ss < 4; ++ss) {
      uint4 u = {bp[ss * 4], bp[ss * 4 + 1], bp[ss * 4 + 2], bp[ss * 4 + 3]};
      s16x8 pb = __builtin_bit_cast(s16x8, u);
      int cx = (ss * 32 + hi * 16) ^ swz;
      s16x8 v0 = *(const s16x8*)(sV[cur] + ql * 128 + cx);
      s16x8 v1 = *(const s16x8*)(sV[cur] + (32 + ql) * 128 + cx);
      oa0 = __builtin_amdgcn_mfma_f32_32x32x16_bf16(v0, pb, oa0, 0, 0, 0);
      oa1 = __builtin_amdgcn_mfma_f32_32x32x16_bf16(v1, pb, oa1, 0, 0, 0);
    }
    __builtin_amdgcn_s_setprio(0);

    ++cur; if (cur == 3) cur = 0;
  }
#undef STAGE

  l_run += __shfl_xor(l_run, 32);
  float inv = 1.f / l_run;
  const int b = bh >> 4, h = bh & 15;
  const int q = q0 + 32 * w + ql;
  unsigned short* crow = Ctx + ((size_t)(b * 2048 + q)) * 1024 + h * 64;
#pragma unroll
  for (int dblk = 0; dblk < 2; ++dblk) {
    const f32x16& oa = dblk ? oa1 : oa0;
#pragma unroll
    for (int grp = 0; grp < 4; ++grp) {
      ushort4 st;
      st.x = f2bf(oa[4 * grp + 0] * inv);
      st.y = f2bf(oa[4 * grp + 1] * inv);
      st.z = f2bf(oa[4 * grp + 2] * inv);
      st.w = f2bf(oa[4 * grp + 3] * inv);
      *(ushort4*)(crow + dblk * 32 + 8 * grp + 4 * hi) = st;
    }
  }
}

extern "C" void kernel_launch(void* const* d_in, const int* in_sizes, int n_in,
                              void* d_out, int out_size, void* d_ws, size_t ws_size,
                              hipStream_t stream) {
  const float* hidden = (const float*)d_in[0];   // (4,2048,1024) f32
  const int*   pos    = (const int*)d_in[1];     // (4,2048) i32
  const float* wqkv   = (const float*)d_in[2];   // (3072,1024) f32
  const float* wo     = (const float*)d_in[3];   // (1024,1024) f32

  char* ws = (char*)d_ws;
  unsigned short* hbf  = (unsigned short*)(ws);                 // 16,777,216 B
  unsigned short* wqbf = (unsigned short*)(ws + 16777216);      //  6,291,456
  unsigned short* wobf = (unsigned short*)(ws + 23068672);      //  2,097,152
  unsigned short* Qr   = (unsigned short*)(ws + 41943040);      // 16,777,216
  unsigned short* Kr   = (unsigned short*)(ws + 58720256);      // 16,777,216
  unsigned short* Vt   = (unsigned short*)(ws + 75497472);      // 16,777,216
  unsigned short* ctx  = (unsigned short*)(ws + 92274688);      // 16,777,216
  float*          ctab = (float*)(ws + 109051904);              //  1,048,576
  float*          stab = (float*)(ws + 110100480);              //  1,048,576
  // total: 111,149,056 B

  cvt_rope_kernel<<<13312, 256, 0, stream>>>(hidden, wqkv, wo, pos,
                                             hbf, wqbf, wobf, ctab, stab);

  dim3 gq(32, 48);
  gemm3_kernel<2><<<gq, 256, 81920, stream>>>(hbf, wqbf, nullptr, 3072, 1024,
                                              ctab, stab, Qr, Kr, Vt);

  dim3 ga(8, 64);
  attn_kernel<<<ga, 512, 0, stream>>>(Qr, Kr, Vt, ctx);

  dim3 go(32, 16);
  gemm3_kernel<1><<<go, 256, 81920, stream>>>(ctx, wobf, d_out, 1024, 1024,
                                              nullptr, nullptr, nullptr, nullptr, nullptr);
}